// Round 5
// baseline (561.316 us; speedup 1.0000x reference)
//
#include <hip/hip_runtime.h>
#include <stdint.h>

#define N_SPK 512
#define N_UTT 64
#define DIM   1024
#define NROWS (N_SPK * N_UTT)   // 32768
#define EPS   1e-6f

#define BM  128
#define BN  128
#define BKB 128                 // K bytes (fp8 elems) per tile
#define KITERS (DIM / BKB)      // 8

typedef __attribute__((ext_vector_type(8))) int   int8v;
typedef __attribute__((ext_vector_type(4))) int   int4v;
typedef __attribute__((ext_vector_type(4))) float f32x4;

// K1: one block per speaker. Wave w streams rows w*16..w*16+15 in 4 rounds of
// 4 rows (16 float4 loads in flight), writes fp8(e4m3) copy + per-row xx.
// Full centroid reduced in-block (LDS), normalized, written as 16*c_hat fp8
// (x16 dodges e4m3 subnormals; folded out as w/16 in the GEMM epilogue).
__global__ __launch_bounds__(256) void prep_full(
    const float* __restrict__ x, uint8_t* __restrict__ xb,
    uint8_t* __restrict__ cmat, float* __restrict__ xxg, float* __restrict__ ssqg)
{
    const int n    = blockIdx.x;
    const int tid  = threadIdx.x;
    const int lane = tid & 63;
    const int w    = tid >> 6;

    const float* xn  = x  + (size_t)n * N_UTT * DIM;
    uint8_t*     xbn = xb + (size_t)n * N_UTT * DIM;

    float Sp[16];
    #pragma unroll
    for (int j = 0; j < 16; ++j) Sp[j] = 0.f;

    for (int rnd = 0; rnd < 4; ++rnd) {
        const int m0 = w * 16 + rnd * 4;

        float4 v[16];
        #pragma unroll
        for (int i = 0; i < 4; ++i)
            #pragma unroll
            for (int j = 0; j < 4; ++j)
                v[i * 4 + j] = *(const float4*)(xn + (size_t)(m0 + i) * DIM + j * 256 + lane * 4);

        float xx[4] = {0.f, 0.f, 0.f, 0.f};
        #pragma unroll
        for (int i = 0; i < 4; ++i) {
            #pragma unroll
            for (int j = 0; j < 4; ++j) {
                const float4 q = v[i * 4 + j];
                xx[i] += q.x * q.x + q.y * q.y + q.z * q.z + q.w * q.w;
                Sp[j * 4 + 0] += q.x; Sp[j * 4 + 1] += q.y;
                Sp[j * 4 + 2] += q.z; Sp[j * 4 + 3] += q.w;
                uint32_t u = (uint32_t)__builtin_amdgcn_cvt_pk_fp8_f32(q.x, q.y, 0, false);
                u = (uint32_t)__builtin_amdgcn_cvt_pk_fp8_f32(q.z, q.w, (int)u, true);
                *(uint32_t*)(xbn + (size_t)(m0 + i) * DIM + j * 256 + lane * 4) = u;
            }
        }

        #pragma unroll
        for (int i = 0; i < 4; ++i) {
            float t = xx[i];
            #pragma unroll
            for (int off = 1; off < 64; off <<= 1) t += __shfl_xor(t, off);
            if (lane == 0) xxg[n * N_UTT + m0 + i] = t;
        }
    }

    // Block reduce of the 4 waves' partial centroids.
    __shared__ float Sh[4][DIM];   // 16 KB
    #pragma unroll
    for (int j = 0; j < 4; ++j)
        *(float4*)&Sh[w][j * 256 + lane * 4] =
            make_float4(Sp[j * 4], Sp[j * 4 + 1], Sp[j * 4 + 2], Sp[j * 4 + 3]);
    __syncthreads();

    const int d0 = tid * 4;
    float4 S = *(const float4*)&Sh[0][d0];
    {
        const float4 b1 = *(const float4*)&Sh[1][d0];
        const float4 b2 = *(const float4*)&Sh[2][d0];
        const float4 b3 = *(const float4*)&Sh[3][d0];
        S.x += b1.x + b2.x + b3.x; S.y += b1.y + b2.y + b3.y;
        S.z += b1.z + b2.z + b3.z; S.w += b1.w + b2.w + b3.w;
    }

    float css = S.x * S.x + S.y * S.y + S.z * S.z + S.w * S.w;
    #pragma unroll
    for (int off = 1; off < 64; off <<= 1) css += __shfl_xor(css, off);
    __shared__ float red[4];
    if ((tid & 63) == 0) red[tid >> 6] = css;
    __syncthreads();
    const float ssq = red[0] + red[1] + red[2] + red[3];

    const float scale = rsqrtf(fmaxf(ssq * (1.0f / 4096.f), EPS)) * (16.0f / 64.f);
    uint32_t u = (uint32_t)__builtin_amdgcn_cvt_pk_fp8_f32(S.x * scale, S.y * scale, 0, false);
    u = (uint32_t)__builtin_amdgcn_cvt_pk_fp8_f32(S.z * scale, S.w * scale, (int)u, true);
    *(uint32_t*)(cmat + (size_t)n * DIM + d0) = u;
    if (tid == 0) ssqg[n] = ssq;
}

// K2: MX-fp8 MFMA GEMM (A = xb [32768 x 1024] e4m3, B^T = cmat [512 x 1024]
// e4m3 = 16*c_hat), scales pinned to 1.0 (E8M0 0x7F). 128x128 tile, BK=128
// bytes, 8 k-iters, global_load_lds width-16, 16B-chunk XOR LDS swizzle.
// b-frags preloaded (32 VGPR), a-frag loaded per-bi (8 VGPR transient);
// __launch_bounds__(256,3) pins >=3 blocks/CU (m114: cross-block overlap
// hides the barrier drain).
__global__ __launch_bounds__(256, 3) void gemm_lse_kernel(
    const uint8_t* __restrict__ xb, const uint8_t* __restrict__ cmat,
    const float* __restrict__ xxg, const float* __restrict__ ssqg,
    const float* __restrict__ wp, const float* __restrict__ bp,
    float* __restrict__ sumexp4, float* __restrict__ pos)
{
    __shared__ __align__(16) uint8_t Asm[BM * BKB];   // 16 KB
    __shared__ __align__(16) uint8_t Bsm[BN * BKB];   // 16 KB
    __shared__ float SeLDS[BM];

    const int tid   = threadIdx.x;
    const int lane  = tid & 63;
    const int wid   = tid >> 6;
    const int waveM = wid >> 1;
    const int waveN = wid & 1;

    const int bid = blockIdx.x;
    const int rt  = (bid & 7) | ((bid >> 5) << 3);
    const int ct  = (bid >> 3) & 3;

    const int rowBase = rt * BM;
    const int colBase = ct * BN;

    // Staging: LDS slot s = i*256+tid holds 16B; its row = s>>3, slot-chunk
    // h' = s&7 stores global chunk h = h' ^ (row&7).
    const uint8_t* gA[4];
    const uint8_t* gB[4];
    #pragma unroll
    for (int i = 0; i < 4; ++i) {
        const int s    = i * 256 + tid;
        const int srow = s >> 3;
        const int h    = (s & 7) ^ (srow & 7);
        gA[i] = xb   + (size_t)(rowBase + srow) * DIM + h * 16;
        gB[i] = cmat + (size_t)(colBase + srow) * DIM + h * 16;
    }

    f32x4 acc[4][4];
    #pragma unroll
    for (int i = 0; i < 4; ++i)
        #pragma unroll
        for (int j = 0; j < 4; ++j)
            acc[i][j] = (f32x4){0.f, 0.f, 0.f, 0.f};

    const int cL  = lane & 15;
    const int q   = lane >> 4;
    // lane's 32B frag = global chunks 2q, 2q+1 of its row -> swizzled slots
    const int fs0 = (2 * q) ^ (cL & 7);
    const int fs1 = fs0 ^ 1;

    for (int kt = 0; kt < KITERS; ++kt) {
        __syncthreads();
        const int ko = kt * BKB;
        #pragma unroll
        for (int i = 0; i < 4; ++i) {
            __builtin_amdgcn_global_load_lds(
                (const __attribute__((address_space(1))) void*)(gA[i] + ko),
                (__attribute__((address_space(3))) void*)(&Asm[(i * 256 + wid * 64) * 16]),
                16, 0, 0);
            __builtin_amdgcn_global_load_lds(
                (const __attribute__((address_space(1))) void*)(gB[i] + ko),
                (__attribute__((address_space(3))) void*)(&Bsm[(i * 256 + wid * 64) * 16]),
                16, 0, 0);
        }
        __syncthreads();

        int8v b[4];
        #pragma unroll
        for (int bj = 0; bj < 4; ++bj) {
            const int row = waveN * 64 + bj * 16 + cL;
            const int4v lo = *(const int4v*)&Bsm[row * BKB + fs0 * 16];
            const int4v hi = *(const int4v*)&Bsm[row * BKB + fs1 * 16];
            b[bj] = __builtin_shufflevector(lo, hi, 0, 1, 2, 3, 4, 5, 6, 7);
        }

        #pragma unroll
        for (int bi = 0; bi < 4; ++bi) {
            const int row = waveM * 64 + bi * 16 + cL;
            const int4v lo = *(const int4v*)&Asm[row * BKB + fs0 * 16];
            const int4v hi = *(const int4v*)&Asm[row * BKB + fs1 * 16];
            const int8v a = __builtin_shufflevector(lo, hi, 0, 1, 2, 3, 4, 5, 6, 7);
            #pragma unroll
            for (int bj = 0; bj < 4; ++bj)
                acc[bi][bj] = __builtin_amdgcn_mfma_scale_f32_16x16x128_f8f6f4(
                    a, b[bj], acc[bi][bj],
                    0, 0,                       // cbsz=FP8(e4m3), blgp=FP8(e4m3)
                    0, 0x7f7f7f7f,              // opsel_a, scale_a = 1.0
                    0, 0x7f7f7f7f);             // opsel_b, scale_b = 1.0
        }
    }

    // Epilogue. dot = 16 * (x . c_hat); fold the 16 into w.
    const float wv = wp[0] * 0.0625f;
    const float bv = bp[0];
    float srow[16];
    #pragma unroll
    for (int bi = 0; bi < 4; ++bi) {
        #pragma unroll
        for (int r = 0; r < 4; ++r) {
            const int R     = rowBase + waveM * 64 + bi * 16 + q * 4 + r;
            const float xxv = xxg[R];
            const float rn  = rsqrtf(fmaxf(xxv, EPS));
            const int nrow  = R >> 6;
            float s = 0.f;
            #pragma unroll
            for (int bj = 0; bj < 4; ++bj) {
                const int col = colBase + waveN * 64 + bj * 16 + cL;
                const float dot = acc[bi][bj][r];
                float sim;
                if (col == nrow) {
                    const float ssqv = ssqg[nrow];
                    const float xs   = dot * sqrtf(ssqv) * 0.0625f;  // x . S
                    const float d2   = ssqv - 2.f * xs + xxv;
                    const float cs   = ((xs - xxv) * (1.f / 63.f)) * rn *
                                       rsqrtf(fmaxf(d2 * (1.f / 3969.f), EPS));
                    sim = wp[0] * cs + bv;
                    pos[R] = sim;
                } else {
                    sim = wv * dot * rn + bv;
                }
                s += __expf(sim);
            }
            #pragma unroll
            for (int off = 1; off < 16; off <<= 1) s += __shfl_xor(s, off);
            srow[bi * 4 + r] = s;
        }
    }

    if (waveN == 1 && cL == 0) {
        #pragma unroll
        for (int bi = 0; bi < 4; ++bi)
            #pragma unroll
            for (int r = 0; r < 4; ++r)
                SeLDS[waveM * 64 + bi * 16 + q * 4 + r] = srow[bi * 4 + r];
    }
    __syncthreads();
    if (waveN == 0 && cL == 0) {
        #pragma unroll
        for (int bi = 0; bi < 4; ++bi)
            #pragma unroll
            for (int r = 0; r < 4; ++r) {
                const int lr = waveM * 64 + bi * 16 + q * 4 + r;
                sumexp4[(size_t)ct * NROWS + rowBase + lr] = srow[bi * 4 + r] + SeLDS[lr];
            }
    }
}

// K3: single block; loss = sum_r log(sum_ct se4) - pos[r].
__global__ __launch_bounds__(1024) void finalize_kernel(
    const float* __restrict__ pos, const float* __restrict__ se4,
    float* __restrict__ out)
{
    const int tid = threadIdx.x;
    float acc = 0.f;
    for (int r = tid; r < NROWS; r += 1024) {
        const float s = se4[r] + se4[NROWS + r] + se4[2 * NROWS + r] + se4[3 * NROWS + r];
        acc += __logf(s) - pos[r];
    }
    #pragma unroll
    for (int off = 1; off < 64; off <<= 1) acc += __shfl_xor(acc, off);
    __shared__ float red[16];
    if ((tid & 63) == 0) red[tid >> 6] = acc;
    __syncthreads();
    if (tid == 0) {
        float t = 0.f;
        #pragma unroll
        for (int i = 0; i < 16; ++i) t += red[i];
        out[0] = t;
    }
}

extern "C" void kernel_launch(void* const* d_in, const int* in_sizes, int n_in,
                              void* d_out, int out_size, void* d_ws, size_t ws_size,
                              hipStream_t stream)
{
    const float* x  = (const float*)d_in[0];
    const float* wp = (const float*)d_in[1];
    const float* bp = (const float*)d_in[2];
    float* out = (float*)d_out;

    char* ws = (char*)d_ws;
    size_t off = 0;
    uint8_t*  xb      = (uint8_t*)(ws + off); off += (size_t)NROWS * DIM;   // 32 MB
    uint8_t*  cmat    = (uint8_t*)(ws + off); off += (size_t)N_SPK * DIM;   // 0.5 MB
    float*    xxg     = (float*)(ws + off);   off += (size_t)NROWS * 4;
    float*    pos     = (float*)(ws + off);   off += (size_t)NROWS * 4;
    float*    sumexp4 = (float*)(ws + off);   off += (size_t)4 * NROWS * 4;
    float*    ssqg    = (float*)(ws + off);   off += (size_t)N_SPK * 4;

    prep_full<<<N_SPK, 256, 0, stream>>>(x, xb, cmat, xxg, ssqg);
    gemm_lse_kernel<<<(NROWS / BM) * (N_SPK / BN), 256, 0, stream>>>(
        xb, cmat, xxg, ssqg, wp, bp, sumexp4, pos);
    finalize_kernel<<<1, 1024, 0, stream>>>(pos, sumexp4, out);
}

// Round 6
// 278.756 us; speedup vs baseline: 2.0136x; 2.0136x over previous
//
#include <hip/hip_runtime.h>
#include <stdint.h>

#define N_SPK 512
#define N_UTT 64
#define DIM   1024
#define NROWS (N_SPK * N_UTT)   // 32768
#define EPS   1e-6f

#define BM  128
#define BN  128
#define BKB 128                 // K bytes (fp8 elems) per tile
#define KITERS (DIM / BKB)      // 8

typedef __attribute__((ext_vector_type(8))) int   int8v;
typedef __attribute__((ext_vector_type(4))) int   int4v;
typedef __attribute__((ext_vector_type(4))) float f32x4;

// K1: one block per speaker. Wave w streams rows w*16..w*16+15 in 4 rounds of
// 4 rows (16 float4 loads in flight), writes fp8(e4m3) copy + per-row xx.
// Full centroid reduced in-block (LDS), normalized, written as 16*c_hat fp8
// (x16 dodges e4m3 subnormals; folded out as w/16 in the GEMM epilogue).
__global__ __launch_bounds__(256) void prep_full(
    const float* __restrict__ x, uint8_t* __restrict__ xb,
    uint8_t* __restrict__ cmat, float* __restrict__ xxg, float* __restrict__ ssqg)
{
    const int n    = blockIdx.x;
    const int tid  = threadIdx.x;
    const int lane = tid & 63;
    const int w    = tid >> 6;

    const float* xn  = x  + (size_t)n * N_UTT * DIM;
    uint8_t*     xbn = xb + (size_t)n * N_UTT * DIM;

    float Sp[16];
    #pragma unroll
    for (int j = 0; j < 16; ++j) Sp[j] = 0.f;

    for (int rnd = 0; rnd < 4; ++rnd) {
        const int m0 = w * 16 + rnd * 4;

        float4 v[16];
        #pragma unroll
        for (int i = 0; i < 4; ++i)
            #pragma unroll
            for (int j = 0; j < 4; ++j)
                v[i * 4 + j] = *(const float4*)(xn + (size_t)(m0 + i) * DIM + j * 256 + lane * 4);

        float xx[4] = {0.f, 0.f, 0.f, 0.f};
        #pragma unroll
        for (int i = 0; i < 4; ++i) {
            #pragma unroll
            for (int j = 0; j < 4; ++j) {
                const float4 q = v[i * 4 + j];
                xx[i] += q.x * q.x + q.y * q.y + q.z * q.z + q.w * q.w;
                Sp[j * 4 + 0] += q.x; Sp[j * 4 + 1] += q.y;
                Sp[j * 4 + 2] += q.z; Sp[j * 4 + 3] += q.w;
                uint32_t u = (uint32_t)__builtin_amdgcn_cvt_pk_fp8_f32(q.x, q.y, 0, false);
                u = (uint32_t)__builtin_amdgcn_cvt_pk_fp8_f32(q.z, q.w, (int)u, true);
                *(uint32_t*)(xbn + (size_t)(m0 + i) * DIM + j * 256 + lane * 4) = u;
            }
        }

        #pragma unroll
        for (int i = 0; i < 4; ++i) {
            float t = xx[i];
            #pragma unroll
            for (int off = 1; off < 64; off <<= 1) t += __shfl_xor(t, off);
            if (lane == 0) xxg[n * N_UTT + m0 + i] = t;
        }
    }

    // Block reduce of the 4 waves' partial centroids.
    __shared__ float Sh[4][DIM];   // 16 KB
    #pragma unroll
    for (int j = 0; j < 4; ++j)
        *(float4*)&Sh[w][j * 256 + lane * 4] =
            make_float4(Sp[j * 4], Sp[j * 4 + 1], Sp[j * 4 + 2], Sp[j * 4 + 3]);
    __syncthreads();

    const int d0 = tid * 4;
    float4 S = *(const float4*)&Sh[0][d0];
    {
        const float4 b1 = *(const float4*)&Sh[1][d0];
        const float4 b2 = *(const float4*)&Sh[2][d0];
        const float4 b3 = *(const float4*)&Sh[3][d0];
        S.x += b1.x + b2.x + b3.x; S.y += b1.y + b2.y + b3.y;
        S.z += b1.z + b2.z + b3.z; S.w += b1.w + b2.w + b3.w;
    }

    float css = S.x * S.x + S.y * S.y + S.z * S.z + S.w * S.w;
    #pragma unroll
    for (int off = 1; off < 64; off <<= 1) css += __shfl_xor(css, off);
    __shared__ float red[4];
    if ((tid & 63) == 0) red[tid >> 6] = css;
    __syncthreads();
    const float ssq = red[0] + red[1] + red[2] + red[3];

    const float scale = rsqrtf(fmaxf(ssq * (1.0f / 4096.f), EPS)) * (16.0f / 64.f);
    uint32_t u = (uint32_t)__builtin_amdgcn_cvt_pk_fp8_f32(S.x * scale, S.y * scale, 0, false);
    u = (uint32_t)__builtin_amdgcn_cvt_pk_fp8_f32(S.z * scale, S.w * scale, (int)u, true);
    *(uint32_t*)(cmat + (size_t)n * DIM + d0) = u;
    if (tid == 0) ssqg[n] = ssq;
}

// K2: MX-fp8 MFMA GEMM (A = xb [32768 x 1024] e4m3, B^T = cmat [512 x 1024]
// e4m3 = 16*c_hat), scales pinned to 1.0 (E8M0 0x7F). 128x128 tile, BK=128
// bytes, 8 k-iters, global_load_lds width-16, 16B-chunk XOR LDS swizzle.
// NOTE: plain __launch_bounds__(256). (256,3) in R5 clamped VGPRs to 84 <
// the 64-reg accumulator -> acc spilled to scratch -> 1 GB HBM traffic,
// 362 us. Let the allocator pick (~150 VGPR, no spill).
__global__ __launch_bounds__(256) void gemm_lse_kernel(
    const uint8_t* __restrict__ xb, const uint8_t* __restrict__ cmat,
    const float* __restrict__ xxg, const float* __restrict__ ssqg,
    const float* __restrict__ wp, const float* __restrict__ bp,
    float* __restrict__ sumexp4, float* __restrict__ pos)
{
    __shared__ __align__(16) uint8_t Asm[BM * BKB];   // 16 KB
    __shared__ __align__(16) uint8_t Bsm[BN * BKB];   // 16 KB
    __shared__ float SeLDS[BM];

    const int tid   = threadIdx.x;
    const int lane  = tid & 63;
    const int wid   = tid >> 6;
    const int waveM = wid >> 1;
    const int waveN = wid & 1;

    const int bid = blockIdx.x;
    const int rt  = (bid & 7) | ((bid >> 5) << 3);
    const int ct  = (bid >> 3) & 3;

    const int rowBase = rt * BM;
    const int colBase = ct * BN;

    // Staging: LDS slot s = i*256+tid holds 16B; its row = s>>3, slot-chunk
    // h' = s&7 stores global chunk h = h' ^ (row&7).
    const uint8_t* gA[4];
    const uint8_t* gB[4];
    #pragma unroll
    for (int i = 0; i < 4; ++i) {
        const int s    = i * 256 + tid;
        const int srow = s >> 3;
        const int h    = (s & 7) ^ (srow & 7);
        gA[i] = xb   + (size_t)(rowBase + srow) * DIM + h * 16;
        gB[i] = cmat + (size_t)(colBase + srow) * DIM + h * 16;
    }

    f32x4 acc[4][4];
    #pragma unroll
    for (int i = 0; i < 4; ++i)
        #pragma unroll
        for (int j = 0; j < 4; ++j)
            acc[i][j] = (f32x4){0.f, 0.f, 0.f, 0.f};

    const int cL  = lane & 15;
    const int q   = lane >> 4;
    // lane's 32B frag = global chunks 2q, 2q+1 of its row -> swizzled slots
    const int fs0 = (2 * q) ^ (cL & 7);
    const int fs1 = fs0 ^ 1;

    for (int kt = 0; kt < KITERS; ++kt) {
        __syncthreads();
        const int ko = kt * BKB;
        #pragma unroll
        for (int i = 0; i < 4; ++i) {
            __builtin_amdgcn_global_load_lds(
                (const __attribute__((address_space(1))) void*)(gA[i] + ko),
                (__attribute__((address_space(3))) void*)(&Asm[(i * 256 + wid * 64) * 16]),
                16, 0, 0);
            __builtin_amdgcn_global_load_lds(
                (const __attribute__((address_space(1))) void*)(gB[i] + ko),
                (__attribute__((address_space(3))) void*)(&Bsm[(i * 256 + wid * 64) * 16]),
                16, 0, 0);
        }
        __syncthreads();

        int8v b[4];
        #pragma unroll
        for (int bj = 0; bj < 4; ++bj) {
            const int row = waveN * 64 + bj * 16 + cL;
            const int4v lo = *(const int4v*)&Bsm[row * BKB + fs0 * 16];
            const int4v hi = *(const int4v*)&Bsm[row * BKB + fs1 * 16];
            b[bj] = __builtin_shufflevector(lo, hi, 0, 1, 2, 3, 4, 5, 6, 7);
        }

        #pragma unroll
        for (int bi = 0; bi < 4; ++bi) {
            const int row = waveM * 64 + bi * 16 + cL;
            const int4v lo = *(const int4v*)&Asm[row * BKB + fs0 * 16];
            const int4v hi = *(const int4v*)&Asm[row * BKB + fs1 * 16];
            const int8v a = __builtin_shufflevector(lo, hi, 0, 1, 2, 3, 4, 5, 6, 7);
            #pragma unroll
            for (int bj = 0; bj < 4; ++bj)
                acc[bi][bj] = __builtin_amdgcn_mfma_scale_f32_16x16x128_f8f6f4(
                    a, b[bj], acc[bi][bj],
                    0, 0,                       // cbsz=FP8(e4m3), blgp=FP8(e4m3)
                    0, 0x7f7f7f7f,              // opsel_a, scale_a = 1.0
                    0, 0x7f7f7f7f);             // opsel_b, scale_b = 1.0
        }
    }

    // Epilogue. dot = 16 * (x . c_hat); fold the 16 into w.
    const float wv = wp[0] * 0.0625f;
    const float bv = bp[0];
    float srow[16];
    #pragma unroll
    for (int bi = 0; bi < 4; ++bi) {
        #pragma unroll
        for (int r = 0; r < 4; ++r) {
            const int R     = rowBase + waveM * 64 + bi * 16 + q * 4 + r;
            const float xxv = xxg[R];
            const float rn  = rsqrtf(fmaxf(xxv, EPS));
            const int nrow  = R >> 6;
            float s = 0.f;
            #pragma unroll
            for (int bj = 0; bj < 4; ++bj) {
                const int col = colBase + waveN * 64 + bj * 16 + cL;
                const float dot = acc[bi][bj][r];
                float sim;
                if (col == nrow) {
                    const float ssqv = ssqg[nrow];
                    const float xs   = dot * sqrtf(ssqv) * 0.0625f;  // x . S
                    const float d2   = ssqv - 2.f * xs + xxv;
                    const float cs   = ((xs - xxv) * (1.f / 63.f)) * rn *
                                       rsqrtf(fmaxf(d2 * (1.f / 3969.f), EPS));
                    sim = wp[0] * cs + bv;
                    pos[R] = sim;
                } else {
                    sim = wv * dot * rn + bv;
                }
                s += __expf(sim);
            }
            #pragma unroll
            for (int off = 1; off < 16; off <<= 1) s += __shfl_xor(s, off);
            srow[bi * 4 + r] = s;
        }
    }

    if (waveN == 1 && cL == 0) {
        #pragma unroll
        for (int bi = 0; bi < 4; ++bi)
            #pragma unroll
            for (int r = 0; r < 4; ++r)
                SeLDS[waveM * 64 + bi * 16 + q * 4 + r] = srow[bi * 4 + r];
    }
    __syncthreads();
    if (waveN == 0 && cL == 0) {
        #pragma unroll
        for (int bi = 0; bi < 4; ++bi)
            #pragma unroll
            for (int r = 0; r < 4; ++r) {
                const int lr = waveM * 64 + bi * 16 + q * 4 + r;
                sumexp4[(size_t)ct * NROWS + rowBase + lr] = srow[bi * 4 + r] + SeLDS[lr];
            }
    }
}

// K3: single block; loss = sum_r log(sum_ct se4) - pos[r].
__global__ __launch_bounds__(1024) void finalize_kernel(
    const float* __restrict__ pos, const float* __restrict__ se4,
    float* __restrict__ out)
{
    const int tid = threadIdx.x;
    float acc = 0.f;
    for (int r = tid; r < NROWS; r += 1024) {
        const float s = se4[r] + se4[NROWS + r] + se4[2 * NROWS + r] + se4[3 * NROWS + r];
        acc += __logf(s) - pos[r];
    }
    #pragma unroll
    for (int off = 1; off < 64; off <<= 1) acc += __shfl_xor(acc, off);
    __shared__ float red[16];
    if ((tid & 63) == 0) red[tid >> 6] = acc;
    __syncthreads();
    if (tid == 0) {
        float t = 0.f;
        #pragma unroll
        for (int i = 0; i < 16; ++i) t += red[i];
        out[0] = t;
    }
}

extern "C" void kernel_launch(void* const* d_in, const int* in_sizes, int n_in,
                              void* d_out, int out_size, void* d_ws, size_t ws_size,
                              hipStream_t stream)
{
    const float* x  = (const float*)d_in[0];
    const float* wp = (const float*)d_in[1];
    const float* bp = (const float*)d_in[2];
    float* out = (float*)d_out;

    char* ws = (char*)d_ws;
    size_t off = 0;
    uint8_t*  xb      = (uint8_t*)(ws + off); off += (size_t)NROWS * DIM;   // 32 MB
    uint8_t*  cmat    = (uint8_t*)(ws + off); off += (size_t)N_SPK * DIM;   // 0.5 MB
    float*    xxg     = (float*)(ws + off);   off += (size_t)NROWS * 4;
    float*    pos     = (float*)(ws + off);   off += (size_t)NROWS * 4;
    float*    sumexp4 = (float*)(ws + off);   off += (size_t)4 * NROWS * 4;
    float*    ssqg    = (float*)(ws + off);   off += (size_t)N_SPK * 4;

    prep_full<<<N_SPK, 256, 0, stream>>>(x, xb, cmat, xxg, ssqg);
    gemm_lse_kernel<<<(NROWS / BM) * (N_SPK / BN), 256, 0, stream>>>(
        xb, cmat, xxg, ssqg, wp, bp, sumexp4, pos);
    finalize_kernel<<<1, 1024, 0, stream>>>(pos, sumexp4, out);
}